// Round 9
// baseline (163.861 us; speedup 1.0000x reference)
//
#include <hip/hip_runtime.h>

#define H 256
#define NB 2048
#define BATCH 8
#define NSPLIT 8
#define KSPAN (NB / NSPLIT)   // 256 keys per split

typedef unsigned short u16;
using bf16x8 = __attribute__((ext_vector_type(8))) __bf16;
using f32x4  = __attribute__((ext_vector_type(4))) float;

typedef const __attribute__((address_space(1))) void gv_t;
typedef __attribute__((address_space(3))) void lv_t;

// async 16B-per-lane global->LDS: lds dst is wave-uniform base, lane i lands at base+16*i
__device__ __forceinline__ void gl_lds16(const void* g, void* l) {
    __builtin_amdgcn_global_load_lds((gv_t*)g, (lv_t*)l, 16, 0, 0);
}

#define MFMA(a, b, c) __builtin_amdgcn_mfma_f32_16x16x32_bf16(a, b, c, 0, 0, 0)

// s_waitcnt vmcnt(N), lgkmcnt/expcnt untouched (gfx9 encoding)
#define WAITV(N) __builtin_amdgcn_s_waitcnt(0xF70 | (N))

__device__ __forceinline__ u16 f2bf(float f) {
    union { float f; unsigned u; } v; v.f = f;
    unsigned r = v.u + 0x7fffu + ((v.u >> 16) & 1u);  // RNE
    return (u16)(r >> 16);
}

// ---- coalesced weight prep (one block per row f):
//   wqb/wkb = bf16(Wq/Wk) row-major; wvw[f] = Wv[f,:]·Ww; kbv[f] = Wk[f,:]·bq ----
__global__ __launch_bounds__(256) void wprep_kernel(
        const float* __restrict__ Wq, const float* __restrict__ Wk,
        const float* __restrict__ Wv, const float* __restrict__ Ww,
        const float* __restrict__ bq,
        u16* __restrict__ wqb, u16* __restrict__ wkb,
        float* __restrict__ wvw, float* __restrict__ kbv) {
    int f = blockIdx.x, t = threadIdx.x;
    float wq = Wq[f * H + t];
    wqb[f * H + t] = f2bf(wq);
    float wk = Wk[f * H + t];
    wkb[f * H + t] = f2bf(wk);
    float p = Wv[f * H + t] * Ww[t];
    float r = wk * bq[t];
    for (int o = 32; o; o >>= 1) { p += __shfl_xor(p, o); r += __shfl_xor(r, o); }
    __shared__ float redp[4], redr[4];
    int w = t >> 6, lane = t & 63;
    if (lane == 0) { redp[w] = p; redr[w] = r; }
    __syncthreads();
    if (t == 0) {
        wvw[f] = redp[0] + redp[1] + redp[2] + redp[3];
        kbv[f] = redr[0] + redr[1] + redr[2] + redr[3];
    }
}

// ---- x -> bf16; per-row: u = x·wvw + bv·Ww, d = (x·kbv)/16, e = exp(d);
//      store uee[row] = {e*u, e}.  One wave per row. ----
__global__ __launch_bounds__(256) void cvtu_kernel(
        const float* __restrict__ x, const float* __restrict__ wvw,
        const float* __restrict__ kbv, const float* __restrict__ bv,
        const float* __restrict__ Ww,
        u16* __restrict__ xbf, float2* __restrict__ uee) {
    int lane = threadIdx.x & 63;
    int row  = blockIdx.x * 4 + (threadIdx.x >> 6);
    float4 xv = *(const float4*)(x + row * H + lane * 4);
    ushort4 o;
    o.x = f2bf(xv.x); o.y = f2bf(xv.y); o.z = f2bf(xv.z); o.w = f2bf(xv.w);
    *(ushort4*)(xbf + row * H + lane * 4) = o;
    float4 wv = *(const float4*)(wvw + lane * 4);
    float s = xv.x * wv.x + xv.y * wv.y + xv.z * wv.z + xv.w * wv.w;
    float4 kv = *(const float4*)(kbv + lane * 4);
    float d = xv.x * kv.x + xv.y * kv.y + xv.z * kv.z + xv.w * kv.w;
    float4 bvv = *(const float4*)(bv + lane * 4);
    float4 www = *(const float4*)(Ww + lane * 4);
    float c = bvv.x * www.x + bvv.y * www.y + bvv.z * www.z + bvv.w * www.w;
    for (int o2 = 32; o2; o2 >>= 1) {
        s += __shfl_xor(s, o2); d += __shfl_xor(d, o2); c += __shfl_xor(c, o2);
    }
    if (lane == 0) {
        float e = __expf(d * 0.0625f);
        uee[row] = make_float2(e * (s + c), e);
    }
}

// ---- generic C = (A @ B^T) * scale, bf16 in/out, MFMA 16x16x32, M=2/wave. ----
__global__ __launch_bounds__(256) void gemm_bt_kernel(
        const u16* __restrict__ A, const u16* __restrict__ B,
        u16* __restrict__ C, float scale) {
    __shared__ u16 bt[16384];   // 32KB fragment-major
    int tid = threadIdx.x;
    int mb = blockIdx.x * 128, nb = blockIdx.y * 64;
    int w = tid >> 6, lane = tid & 63;
    int l15 = lane & 15, quad = lane >> 4;

    {   // wave w stages t=w, ks=0..7
        const u16* gsrc = B + (nb + w * 16 + l15) * H + quad * 8;
        for (int ks = 0; ks < 8; ++ks)
            gl_lds16(gsrc + ks * 32, bt + (w * 8 + ks) * 512);
    }

    bf16x8 a[2][8];
    for (int mi = 0; mi < 2; ++mi) {
        const u16* abase = A + (size_t)(mb + w * 32 + mi * 16 + l15) * H + quad * 8;
        for (int ks = 0; ks < 8; ++ks) a[mi][ks] = *(const bf16x8*)(abase + ks * 32);
    }
    __syncthreads();

    f32x4 acc[2][4] = {};
    for (int ks = 0; ks < 8; ++ks)
        for (int t = 0; t < 4; ++t) {
            bf16x8 b = *(const bf16x8*)(bt + ((t * 8 + ks) * 64 + lane) * 8);
            acc[0][t] = MFMA(a[0][ks], b, acc[0][t]);
            acc[1][t] = MFMA(a[1][ks], b, acc[1][t]);
        }

    for (int mi = 0; mi < 2; ++mi) {
        int m = mb + w * 32 + mi * 16 + quad * 4;
        for (int t = 0; t < 4; ++t) {
            int n = nb + t * 16 + l15;
            for (int r = 0; r < 4; ++r)
                C[(size_t)(m + r) * H + n] = f2bf(acc[mi][t][r] * scale);
        }
    }
}

// ---- attention: logit(n,m) = T[n]·x[m]; num += e^logit·(e·u)_m, den += e^logit·e_m.
//      Single-wave blocks (64 thr), M=4 (64 q-rows resident), NO LDS, NO barriers.
//      Keys stream global->VGPR in 4-load groups (K split 2x128) self-paced with
//      s_waitcnt vmcnt(5): prefetch depth 9 loads, never a vmcnt(0) drain.
//      ALL 16 key-tiles macro-emitted explicitly — no runtime-indexed register
//      arrays (R6/R7: dynamic indices -> alloca -> 21-93MB scratch traffic).
//      b in low 3 bits of blockIdx pins batch b -> XCD b (working set 2MB < 4MB L2). ----
__global__ __launch_bounds__(64, 2) void attn_kernel(
        const u16* __restrict__ T, const u16* __restrict__ xbf,
        const float2* __restrict__ uee,
        float* __restrict__ pnum, float* __restrict__ pden) {
    int id = blockIdx.x;
    int b = id & 7, rest = id >> 3;
    int qt = rest & 31, sp = rest >> 5;   // 32 q-tiles x 8 splits
    int lane = threadIdx.x;
    int l15 = lane & 15, quad = lane >> 4;

    // resident A fragments: 64 q-rows (4 x 16), 128 VGPRs
    bf16x8 aq[4][8];
    {
        const u16* qbase = T + (size_t)(b * NB + qt * 64 + l15) * H + quad * 8;
        #pragma unroll
        for (int mi = 0; mi < 4; ++mi)
            #pragma unroll
            for (int ks = 0; ks < 8; ++ks)
                aq[mi][ks] = *(const bf16x8*)(qbase + mi * 16 * H + ks * 32);
    }

    const u16* xb = xbf + ((size_t)b * NB + sp * KSPAN) * H;
    const float2* uep = uee + (size_t)b * NB + sp * KSPAN;

    bf16x8 Ab[4], Bb[4];   // constant-indexed only (unrolled) -> stay in VGPRs
    f32x4 acc[4];
    float2 uva, uvb;
    float ls[4][4] = {}, as_[4][4] = {};

#define LDA(t) { const u16* p_ = xb + (size_t)((t) * 16 + l15) * H + quad * 8; \
    Ab[0] = *(const bf16x8*)(p_);      Ab[1] = *(const bf16x8*)(p_ + 32); \
    Ab[2] = *(const bf16x8*)(p_ + 64); Ab[3] = *(const bf16x8*)(p_ + 96); }
#define LDB(t) { const u16* p_ = xb + (size_t)((t) * 16 + l15) * H + 128 + quad * 8; \
    Bb[0] = *(const bf16x8*)(p_);      Bb[1] = *(const bf16x8*)(p_ + 32); \
    Bb[2] = *(const bf16x8*)(p_ + 64); Bb[3] = *(const bf16x8*)(p_ + 96); }

#define TILE(t, UVC, UVN, WG0, WG1) { \
    WAITV(WG0); \
    _Pragma("unroll") for (int mi = 0; mi < 4; ++mi) acc[mi] = (f32x4){0.f, 0.f, 0.f, 0.f}; \
    _Pragma("unroll") for (int kk = 0; kk < 4; ++kk) { \
        _Pragma("unroll") for (int mi = 0; mi < 4; ++mi) \
            acc[mi] = MFMA(aq[mi][kk], Ab[kk], acc[mi]); } \
    if ((t) < 15) { LDA((t) + 1); UVN = uep[((t) + 1) * 16 + l15]; } \
    WAITV(WG1); \
    _Pragma("unroll") for (int kk = 0; kk < 4; ++kk) { \
        _Pragma("unroll") for (int mi = 0; mi < 4; ++mi) \
            acc[mi] = MFMA(aq[mi][4 + kk], Bb[kk], acc[mi]); } \
    if ((t) < 15) LDB((t) + 1); \
    _Pragma("unroll") for (int mi = 0; mi < 4; ++mi) { \
        _Pragma("unroll") for (int r = 0; r < 4; ++r) { \
            float p_e = __expf(acc[mi][r]); \
            as_[mi][r] += p_e * UVC.x; ls[mi][r] += p_e * UVC.y; } } }

    LDA(0); uva = uep[l15]; LDB(0);

    TILE(0,  uva, uvb, 5, 5)
    TILE(1,  uvb, uva, 5, 5)
    TILE(2,  uva, uvb, 5, 5)
    TILE(3,  uvb, uva, 5, 5)
    TILE(4,  uva, uvb, 5, 5)
    TILE(5,  uvb, uva, 5, 5)
    TILE(6,  uva, uvb, 5, 5)
    TILE(7,  uvb, uva, 5, 5)
    TILE(8,  uva, uvb, 5, 5)
    TILE(9,  uvb, uva, 5, 5)
    TILE(10, uva, uvb, 5, 5)
    TILE(11, uvb, uva, 5, 5)
    TILE(12, uva, uvb, 5, 5)
    TILE(13, uvb, uva, 5, 5)
    TILE(14, uva, uvb, 5, 5)
    TILE(15, uvb, uva, 4, 0)

#undef TILE
#undef LDA
#undef LDB

    // reduce over the 16 key-columns (l15)
    #pragma unroll
    for (int mi = 0; mi < 4; ++mi)
        #pragma unroll
        for (int r = 0; r < 4; ++r)
            for (int o = 1; o < 16; o <<= 1) {
                ls[mi][r]  += __shfl_xor(ls[mi][r], o);
                as_[mi][r] += __shfl_xor(as_[mi][r], o);
            }

    if (l15 == 0) {
        size_t base = (size_t)(sp * BATCH + b) * NB + qt * 64 + quad * 4;
        #pragma unroll
        for (int mi = 0; mi < 4; ++mi)
            #pragma unroll
            for (int r = 0; r < 4; ++r) {
                pnum[base + mi * 16 + r] = as_[mi][r];
                pden[base + mi * 16 + r] = ls[mi][r];
            }
    }
}

// ---- combine K-splits: out = sum(num)/sum(den) + bw ----
__global__ __launch_bounds__(256) void finalize_kernel(
        const float* __restrict__ pnum, const float* __restrict__ pden,
        const float* __restrict__ bw, float* __restrict__ out) {
    int i = blockIdx.x * 256 + threadIdx.x;   // i = b*NB + n
    float num = 0.f, den = 0.f;
    for (int sp = 0; sp < NSPLIT; ++sp) {
        num += pnum[sp * (BATCH * NB) + i];
        den += pden[sp * (BATCH * NB) + i];
    }
    out[i] = num / den + bw[0];
}

extern "C" void kernel_launch(void* const* d_in, const int* in_sizes, int n_in,
                              void* d_out, int out_size, void* d_ws, size_t ws_size,
                              hipStream_t stream) {
    (void)in_sizes; (void)n_in; (void)out_size; (void)ws_size;
    const float* x  = (const float*)d_in[0];
    const float* Wq = (const float*)d_in[1];
    const float* bq = (const float*)d_in[2];
    const float* Wk = (const float*)d_in[3];
    const float* bk = (const float*)d_in[4];  (void)bk;  // cancels in softmax
    const float* Wv = (const float*)d_in[5];
    const float* bv = (const float*)d_in[6];
    const float* Ww = (const float*)d_in[7];
    const float* bw = (const float*)d_in[8];
    float* out = (float*)d_out;

    u16* xbf = (u16*)d_ws;                     // 4194304 u16 (8 MB)
    u16* Tbf = xbf + 4194304;                  // 4194304 u16 (8 MB)
    u16* aTb = Tbf + 4194304;                  // 65536 u16
    u16* wqb = aTb + 65536;                    // 65536 u16
    u16* wkb = wqb + 65536;                    // 65536 u16
    float* wvw = (float*)(wkb + 65536);        // 256 f32
    float* kbv = wvw + 256;                    // 256 f32
    float2* uee = (float2*)(kbv + 256);        // 16384 float2
    float* pnum = (float*)(uee + 16384);       // NSPLIT*16384 f32
    float* pden = pnum + NSPLIT * BATCH * NB;  // NSPLIT*16384 f32

    hipLaunchKernelGGL(wprep_kernel, dim3(256), dim3(256), 0, stream,
                       Wq, Wk, Wv, Ww, bq, wqb, wkb, wvw, kbv);
    // aT[f][e] = (Wk[f,:]·Wq[e,:])/16
    hipLaunchKernelGGL(gemm_bt_kernel, dim3(2, 4), dim3(256), 0, stream,
                       wkb, wqb, aTb, 0.0625f);
    hipLaunchKernelGGL(cvtu_kernel, dim3(4096), dim3(256), 0, stream,
                       x, wvw, kbv, bv, Ww, xbf, uee);
    // T = xbf @ aT^T (aTb rows are B-operand rows)
    hipLaunchKernelGGL(gemm_bt_kernel, dim3(128, 4), dim3(256), 0, stream,
                       xbf, aTb, Tbf, 1.0f);
    hipLaunchKernelGGL(attn_kernel, dim3(8 * 32 * NSPLIT), dim3(64), 0, stream,
                       Tbf, xbf, uee, pnum, pden);
    hipLaunchKernelGGL(finalize_kernel, dim3(64), dim3(256), 0, stream,
                       pnum, pden, bw, out);
}